// Round 9
// baseline (292.823 us; speedup 1.0000x reference)
//
#include <hip/hip_runtime.h>

#define NUSERS 100000
#define NITEMS 50000
#define NNODES 150000
#define DIM 64
#define E0 600000
#define E2 (2 * E0)
#define BB 8192
#define LW 1e-4f
#define NN16 150016
#define NB 586      // cdiv(NNODES, 256)
#define LOSS_BLOCKS 128
#define UBLK 6250   // cdiv(NUSERS, 16)  (16 nodes per 512-thr block)
#define IBLK 3125   // cdiv(NITEMS, 16)
#define PLACE_B 2344  // cdiv(E0, 256)

// ---- bf16 helpers (fp32 <-> packed bf16 pair in a uint) ----
__device__ __forceinline__ float bf_lo(unsigned u) { return __uint_as_float(u << 16); }
__device__ __forceinline__ float bf_hi(unsigned u) { return __uint_as_float(u & 0xffff0000u); }
__device__ __forceinline__ unsigned rne16(float x) {
  unsigned u = __float_as_uint(x);
  return (u + 0x7fffu + ((u >> 16) & 1u)) >> 16;
}
__device__ __forceinline__ unsigned pack2(float lo, float hi) {
  return rne16(lo) | (rne16(hi) << 16);
}

__global__ void k_zero_i(int* __restrict__ p, int n) {
  int i = blockIdx.x * blockDim.x + threadIdx.x;
  if (i < n) p[i] = 0;
}

// Degree count; atomic return value IS the edge's rank within its row.
// ~50us floor: 1.2M device-scope returning atomics at the fabric coherence
// point (~24 Gop/s). Sharding proven NOT to help (R8).
__global__ void k_count_deg(const int* __restrict__ eu, const int* __restrict__ ei,
                            int* __restrict__ deg, int* __restrict__ ru,
                            int* __restrict__ ri) {
  int e = blockIdx.x * blockDim.x + threadIdx.x;
  if (e < E0) {
    ru[e] = atomicAdd(&deg[eu[e]], 1);
    ri[e] = atomicAdd(&deg[NUSERS + ei[e]], 1);
  }
}

// Scan pass 1: block-local exclusive scan of deg -> ptr, block sums -> blk.
__global__ void k_scan1(const int* __restrict__ deg, int* __restrict__ ptr,
                        int* __restrict__ blk) {
  __shared__ int s[256];
  int g = blockIdx.x * 256 + threadIdx.x;
  int v = (g < NNODES) ? deg[g] : 0;
  s[threadIdx.x] = v;
  __syncthreads();
  for (int off = 1; off < 256; off <<= 1) {
    int t = 0;
    if ((int)threadIdx.x >= off) t = s[threadIdx.x - off];
    __syncthreads();
    if ((int)threadIdx.x >= off) s[threadIdx.x] += t;
    __syncthreads();
  }
  if (g < NNODES) ptr[g] = s[threadIdx.x] - v;
  if (threadIdx.x == 255) blk[blockIdx.x] = s[255];
}

// Fused scan-fixup + dinv + scaled-cast. Each block: (a) reduces the block
// sums of all predecessor blocks (586 ints — redundant but trivial), (b)
// finalizes ptr for its 256 nodes, (c) computes dinv into LDS + global,
// (d) casts its nodes' rows: s0 = dinv * x in bf16.
__global__ void k_scan_fix_cast(int* __restrict__ ptr, const int* __restrict__ blk,
                                const int* __restrict__ deg, float* __restrict__ dinv,
                                const float4* __restrict__ Gu4,
                                const float4* __restrict__ Gi4,
                                uint2* __restrict__ h0) {
  __shared__ float sdinv[256];
  __shared__ int swsum[4];
  __shared__ int sPre;
  int tid = threadIdx.x;
  // (a) predecessor block-sum reduce
  int part = 0;
  for (int j = tid; j < (int)blockIdx.x; j += 256) part += blk[j];
  for (int off = 32; off > 0; off >>= 1) part += __shfl_down(part, off);
  if ((tid & 63) == 0) swsum[tid >> 6] = part;
  __syncthreads();
  if (tid == 0) sPre = swsum[0] + swsum[1] + swsum[2] + swsum[3];
  __syncthreads();
  int presum = sPre;
  // (b,c) ptr fixup + dinv
  int g = blockIdx.x * 256 + tid;
  float dv = 0.0f;
  if (g < NNODES) {
    ptr[g] += presum;
    int d = deg[g];
    dv = d > 0 ? rsqrtf((float)d) : 0.0f;
    dinv[g] = dv;
  }
  sdinv[tid] = dv;
  __syncthreads();
  // (d) cast this block's 256 nodes (4096 float4 elements)
  int fbase = blockIdx.x * 256 * 16;
  #pragma unroll
  for (int k = 0; k < 16; ++k) {
    int f = fbase + k * 256 + tid;
    if (f < NNODES * 16) {
      float s = sdinv[(f >> 4) - blockIdx.x * 256];
      float4 v = (f < NUSERS * 16) ? Gu4[f] : Gi4[f - NUSERS * 16];
      h0[f] = make_uint2(pack2(s * v.x, s * v.y), pack2(s * v.z, s * v.w));
    }
  }
}

// CSR column placement using precomputed ranks — NO atomics.
__global__ void k_place(const int* __restrict__ eu, const int* __restrict__ ei,
                        const int* __restrict__ ptr, const int* __restrict__ ru,
                        const int* __restrict__ ri, int* __restrict__ col) {
  int e = blockIdx.x * blockDim.x + threadIdx.x;
  if (e < E0) {
    int u = eu[e];
    int it = NUSERS + ei[e];
    col[ptr[u] + ru[e]] = it;
    col[ptr[it] + ri[e]] = u;
  }
}

// Scaled-space SpMM: s_out(n) = dinv(n)^2 * sum_{c in N(n)} s_in(c).
// 2 nodes per wave; lane = 8*sub + q (8 neighbor rows in flight / node).
__global__ __launch_bounds__(512) void k_spmm2(
    const int* __restrict__ ptr, const int* __restrict__ deg,
    const int* __restrict__ col, const float* __restrict__ dinv,
    const uint4* __restrict__ h, uint4* __restrict__ hout) {
  int wid = threadIdx.x >> 6;
  int lane = threadIdx.x & 63;
  int sub = lane >> 3;
  int q = lane & 7;
  int gA, coff;
  const uint4* hsrc;
  if (blockIdx.x < UBLK) {           // user dst gather from item half
    gA = blockIdx.x * 16 + wid * 2;
    coff = NUSERS;
    hsrc = h + (size_t)NUSERS * 8;
  } else {                            // item dst gather from user half
    gA = NUSERS + (blockIdx.x - UBLK) * 16 + wid * 2;
    coff = 0;
    hsrc = h;
  }
  int gB = gA + 1;
  int stA = ptr[gA], dgA = deg[gA];
  int stB = ptr[gB], dgB = deg[gB];
  float dnA = dinv[gA], dnB = dinv[gB];
  int cA = (sub < dgA) ? col[stA + sub] : -1;
  int cB = (sub < dgB) ? col[stB + sub] : -1;
  uint4 xA = {0, 0, 0, 0}, xB = {0, 0, 0, 0};
  if (cA >= 0) xA = hsrc[(size_t)(cA - coff) * 8 + q];
  if (cB >= 0) xB = hsrc[(size_t)(cB - coff) * 8 + q];
  float aA0 = bf_lo(xA.x), aA1 = bf_hi(xA.x), aA2 = bf_lo(xA.y), aA3 = bf_hi(xA.y);
  float aA4 = bf_lo(xA.z), aA5 = bf_hi(xA.z), aA6 = bf_lo(xA.w), aA7 = bf_hi(xA.w);
  float aB0 = bf_lo(xB.x), aB1 = bf_hi(xB.x), aB2 = bf_lo(xB.y), aB3 = bf_hi(xB.y);
  float aB4 = bf_lo(xB.z), aB5 = bf_hi(xB.z), aB6 = bf_lo(xB.w), aB7 = bf_hi(xB.w);
  for (int j = stA + 8 + sub; j < stA + dgA; j += 8) {
    int c = col[j];
    uint4 x = hsrc[(size_t)(c - coff) * 8 + q];
    aA0 += bf_lo(x.x); aA1 += bf_hi(x.x); aA2 += bf_lo(x.y); aA3 += bf_hi(x.y);
    aA4 += bf_lo(x.z); aA5 += bf_hi(x.z); aA6 += bf_lo(x.w); aA7 += bf_hi(x.w);
  }
  for (int j = stB + 8 + sub; j < stB + dgB; j += 8) {
    int c = col[j];
    uint4 x = hsrc[(size_t)(c - coff) * 8 + q];
    aB0 += bf_lo(x.x); aB1 += bf_hi(x.x); aB2 += bf_lo(x.y); aB3 += bf_hi(x.y);
    aB4 += bf_lo(x.z); aB5 += bf_hi(x.z); aB6 += bf_lo(x.w); aB7 += bf_hi(x.w);
  }
  #pragma unroll
  for (int m = 8; m <= 32; m <<= 1) {
    aA0 += __shfl_xor(aA0, m); aA1 += __shfl_xor(aA1, m);
    aA2 += __shfl_xor(aA2, m); aA3 += __shfl_xor(aA3, m);
    aA4 += __shfl_xor(aA4, m); aA5 += __shfl_xor(aA5, m);
    aA6 += __shfl_xor(aA6, m); aA7 += __shfl_xor(aA7, m);
    aB0 += __shfl_xor(aB0, m); aB1 += __shfl_xor(aB1, m);
    aB2 += __shfl_xor(aB2, m); aB3 += __shfl_xor(aB3, m);
    aB4 += __shfl_xor(aB4, m); aB5 += __shfl_xor(aB5, m);
    aB6 += __shfl_xor(aB6, m); aB7 += __shfl_xor(aB7, m);
  }
  if (sub == 0) {
    float sA = dnA * dnA;
    float sB = dnB * dnB;
    hout[(size_t)gA * 8 + q] = make_uint4(pack2(aA0 * sA, aA1 * sA), pack2(aA2 * sA, aA3 * sA),
                                          pack2(aA4 * sA, aA5 * sA), pack2(aA6 * sA, aA7 * sA));
    hout[(size_t)gB * 8 + q] = make_uint4(pack2(aB0 * sB, aB1 * sB), pack2(aB2 * sB, aB3 * sB),
                                          pack2(aB4 * sB, aB5 * sB), pack2(aB6 * sB, aB7 * sB));
  }
}

__device__ __forceinline__ int decode_node(int k, const int* __restrict__ usr,
                                           const int* __restrict__ pos,
                                           const int* __restrict__ neg, int* coff) {
  if (k < BB) { *coff = NUSERS; return usr[k]; }
  if (k < 2 * BB) { *coff = 0; return NUSERS + pos[k - BB]; }
  *coff = 0; return NUSERS + neg[k - 2 * BB];
}

// Layer-3 SpMM only at the <=3*BB batch nodes (duplicate writes identical).
__global__ __launch_bounds__(512) void k_spmm_batch(
    const int* __restrict__ usr, const int* __restrict__ pos, const int* __restrict__ neg,
    const int* __restrict__ ptr, const int* __restrict__ deg,
    const int* __restrict__ col, const float* __restrict__ dinv,
    const uint4* __restrict__ h, uint4* __restrict__ hout) {
  int wid = threadIdx.x >> 6;
  int lane = threadIdx.x & 63;
  int sub = lane >> 3;
  int q = lane & 7;
  int k0 = blockIdx.x * 16 + wid * 2;
  int cofA, cofB;
  int gA = decode_node(k0, usr, pos, neg, &cofA);
  int gB = decode_node(k0 + 1, usr, pos, neg, &cofB);
  const uint4* hsA = h + (size_t)cofA * 8;
  const uint4* hsB = h + (size_t)cofB * 8;
  int stA = ptr[gA], dgA = deg[gA];
  int stB = ptr[gB], dgB = deg[gB];
  float dnA = dinv[gA], dnB = dinv[gB];
  int cA = (sub < dgA) ? col[stA + sub] : -1;
  int cB = (sub < dgB) ? col[stB + sub] : -1;
  uint4 xA = {0, 0, 0, 0}, xB = {0, 0, 0, 0};
  if (cA >= 0) xA = hsA[(size_t)(cA - cofA) * 8 + q];
  if (cB >= 0) xB = hsB[(size_t)(cB - cofB) * 8 + q];
  float aA0 = bf_lo(xA.x), aA1 = bf_hi(xA.x), aA2 = bf_lo(xA.y), aA3 = bf_hi(xA.y);
  float aA4 = bf_lo(xA.z), aA5 = bf_hi(xA.z), aA6 = bf_lo(xA.w), aA7 = bf_hi(xA.w);
  float aB0 = bf_lo(xB.x), aB1 = bf_hi(xB.x), aB2 = bf_lo(xB.y), aB3 = bf_hi(xB.y);
  float aB4 = bf_lo(xB.z), aB5 = bf_hi(xB.z), aB6 = bf_lo(xB.w), aB7 = bf_hi(xB.w);
  for (int j = stA + 8 + sub; j < stA + dgA; j += 8) {
    int c = col[j];
    uint4 x = hsA[(size_t)(c - cofA) * 8 + q];
    aA0 += bf_lo(x.x); aA1 += bf_hi(x.x); aA2 += bf_lo(x.y); aA3 += bf_hi(x.y);
    aA4 += bf_lo(x.z); aA5 += bf_hi(x.z); aA6 += bf_lo(x.w); aA7 += bf_hi(x.w);
  }
  for (int j = stB + 8 + sub; j < stB + dgB; j += 8) {
    int c = col[j];
    uint4 x = hsB[(size_t)(c - cofB) * 8 + q];
    aB0 += bf_lo(x.x); aB1 += bf_hi(x.x); aB2 += bf_lo(x.y); aB3 += bf_hi(x.y);
    aB4 += bf_lo(x.z); aB5 += bf_hi(x.z); aB6 += bf_lo(x.w); aB7 += bf_hi(x.w);
  }
  #pragma unroll
  for (int m = 8; m <= 32; m <<= 1) {
    aA0 += __shfl_xor(aA0, m); aA1 += __shfl_xor(aA1, m);
    aA2 += __shfl_xor(aA2, m); aA3 += __shfl_xor(aA3, m);
    aA4 += __shfl_xor(aA4, m); aA5 += __shfl_xor(aA5, m);
    aA6 += __shfl_xor(aA6, m); aA7 += __shfl_xor(aA7, m);
    aB0 += __shfl_xor(aB0, m); aB1 += __shfl_xor(aB1, m);
    aB2 += __shfl_xor(aB2, m); aB3 += __shfl_xor(aB3, m);
    aB4 += __shfl_xor(aB4, m); aB5 += __shfl_xor(aB5, m);
    aB6 += __shfl_xor(aB6, m); aB7 += __shfl_xor(aB7, m);
  }
  if (sub == 0) {
    float sA = dnA * dnA;
    float sB = dnB * dnB;
    hout[(size_t)gA * 8 + q] = make_uint4(pack2(aA0 * sA, aA1 * sA), pack2(aA2 * sA, aA3 * sA),
                                          pack2(aA4 * sA, aA5 * sA), pack2(aA6 * sA, aA7 * sA));
    hout[(size_t)gB * 8 + q] = make_uint4(pack2(aB0 * sB, aB1 * sB), pack2(aB2 * sB, aB3 * sB),
                                          pack2(aB4 * sB, aB5 * sB), pack2(aB6 * sB, aB7 * sB));
  }
}

// Fused batch gather + layer sum + BPR loss + last-block final reduce.
__global__ void k_loss(const int* __restrict__ usr, const int* __restrict__ pos,
                       const int* __restrict__ neg, const int* __restrict__ deg,
                       const float4* __restrict__ Gu4, const float4* __restrict__ Gi4,
                       const uint2* __restrict__ h1, const uint2* __restrict__ h2,
                       const uint2* __restrict__ h3, float* __restrict__ bpart,
                       int* __restrict__ cnt, float* __restrict__ out) {
  __shared__ float sL[4], sR[4];
  __shared__ int sDone;
  int wid = threadIdx.x >> 6;
  int lane = threadIdx.x & 63;
  int r = lane >> 4;
  int q = lane & 15;
  int gw = blockIdx.x * 4 + wid;
  int nw = gridDim.x * 4;
  const float s = 0.25f;
  float accL = 0.0f, accR = 0.0f;
  for (int b4 = gw; b4 < BB / 4; b4 += nw) {
    int b = b4 * 4 + r;
    int iu = usr[b], ip = pos[b], ig = neg[b];
    float sdu = sqrtf((float)deg[iu]);
    float sdp = sqrtf((float)deg[NUSERS + ip]);
    float sdn = sqrtf((float)deg[NUSERS + ig]);
    size_t ou = (size_t)iu * 16 + q;
    size_t op = ((size_t)NUSERS + ip) * 16 + q;
    size_t on = ((size_t)NUSERS + ig) * 16 + q;
    float4 u = Gu4[ou];
    float4 p = Gi4[(size_t)ip * 16 + q];
    float4 g = Gi4[(size_t)ig * 16 + q];
    float4 su = {0, 0, 0, 0}, sp = {0, 0, 0, 0}, sg = {0, 0, 0, 0};
    uint2 v;
    v = h1[ou]; su.x += bf_lo(v.x); su.y += bf_hi(v.x); su.z += bf_lo(v.y); su.w += bf_hi(v.y);
    v = h2[ou]; su.x += bf_lo(v.x); su.y += bf_hi(v.x); su.z += bf_lo(v.y); su.w += bf_hi(v.y);
    v = h3[ou]; su.x += bf_lo(v.x); su.y += bf_hi(v.x); su.z += bf_lo(v.y); su.w += bf_hi(v.y);
    v = h1[op]; sp.x += bf_lo(v.x); sp.y += bf_hi(v.x); sp.z += bf_lo(v.y); sp.w += bf_hi(v.y);
    v = h2[op]; sp.x += bf_lo(v.x); sp.y += bf_hi(v.x); sp.z += bf_lo(v.y); sp.w += bf_hi(v.y);
    v = h3[op]; sp.x += bf_lo(v.x); sp.y += bf_hi(v.x); sp.z += bf_lo(v.y); sp.w += bf_hi(v.y);
    v = h1[on]; sg.x += bf_lo(v.x); sg.y += bf_hi(v.x); sg.z += bf_lo(v.y); sg.w += bf_hi(v.y);
    v = h2[on]; sg.x += bf_lo(v.x); sg.y += bf_hi(v.x); sg.z += bf_lo(v.y); sg.w += bf_hi(v.y);
    v = h3[on]; sg.x += bf_lo(v.x); sg.y += bf_hi(v.x); sg.z += bf_lo(v.y); sg.w += bf_hi(v.y);
    u.x = (u.x + sdu * su.x) * s; u.y = (u.y + sdu * su.y) * s;
    u.z = (u.z + sdu * su.z) * s; u.w = (u.w + sdu * su.w) * s;
    p.x = (p.x + sdp * sp.x) * s; p.y = (p.y + sdp * sp.y) * s;
    p.z = (p.z + sdp * sp.z) * s; p.w = (p.w + sdp * sp.w) * s;
    g.x = (g.x + sdn * sg.x) * s; g.y = (g.y + sdn * sg.y) * s;
    g.z = (g.z + sdn * sg.z) * s; g.w = (g.w + sdn * sg.w) * s;
    float dp = u.x * p.x + u.y * p.y + u.z * p.z + u.w * p.w;
    float dn = u.x * g.x + u.y * g.y + u.z * g.z + u.w * g.w;
    float rg = u.x * u.x + u.y * u.y + u.z * u.z + u.w * u.w
             + p.x * p.x + p.y * p.y + p.z * p.z + p.w * p.w
             + g.x * g.x + g.y * g.y + g.z * g.z + g.w * g.w;
    #pragma unroll
    for (int m = 1; m <= 8; m <<= 1) {
      dp += __shfl_xor(dp, m);
      dn += __shfl_xor(dn, m);
      rg += __shfl_xor(rg, m);
    }
    if (q == 0) {
      float diff = dp - dn;
      accL -= fminf(diff, 0.0f) - log1pf(expf(-fabsf(diff)));
      accR += rg;
    }
  }
  accL += __shfl_xor(accL, 16); accR += __shfl_xor(accR, 16);
  accL += __shfl_xor(accL, 32); accR += __shfl_xor(accR, 32);
  if (lane == 0) { sL[wid] = accL; sR[wid] = accR; }
  __syncthreads();
  if (threadIdx.x == 0) {
    bpart[blockIdx.x] = sL[0] + sL[1] + sL[2] + sL[3];
    bpart[LOSS_BLOCKS + blockIdx.x] = sR[0] + sR[1] + sR[2] + sR[3];
    __threadfence();
    sDone = (atomicAdd(cnt, 1) == LOSS_BLOCKS - 1) ? 1 : 0;
  }
  __syncthreads();
  if (sDone && threadIdx.x < 64) {
    __threadfence();  // acquire: other blocks' bpart stores
    int ln = threadIdx.x;
    float l = bpart[ln] + bpart[ln + 64];
    float rr = bpart[LOSS_BLOCKS + ln] + bpart[LOSS_BLOCKS + ln + 64];
    for (int off = 32; off > 0; off >>= 1) {
      l += __shfl_down(l, off);
      rr += __shfl_down(rr, off);
    }
    if (ln == 0) out[0] = l * (1.0f / BB) + LW * 0.5f * rr * (1.0f / BB);
  }
}

extern "C" void kernel_launch(void* const* d_in, const int* in_sizes, int n_in,
                              void* d_out, int out_size, void* d_ws, size_t ws_size,
                              hipStream_t stream) {
  const float* Gu = (const float*)d_in[0];
  const float* Gi = (const float*)d_in[1];
  const int* eu  = (const int*)d_in[2];
  const int* ei  = (const int*)d_in[3];
  const int* usr = (const int*)d_in[4];
  const int* pos = (const int*)d_in[5];
  const int* neg = (const int*)d_in[6];
  float* out = (float*)d_out;

  // Workspace: ~8 MB ints + 57.6 MB h (h3 reuses h0) = ~66 MB.
  int* deg   = (int*)d_ws;                 // NN16
  int* cnt   = deg + NN16;                 // 16 (zeroed with deg)
  int* ptr   = cnt + 16;                   // NN16
  int* blk   = ptr + NN16;                 // 1024
  int* ru    = blk + 1024;                 // E0
  int* ri    = ru + E0;                    // E0
  int* col   = ri + E0;                    // E2
  float* dinv = (float*)(col + E2);        // NN16
  uint2* h0  = (uint2*)(dinv + NN16);      // NNODES*16 uint2 each (19.2 MB)
  uint2* h1  = h0 + (size_t)NNODES * 16;
  uint2* h2  = h1 + (size_t)NNODES * 16;
  uint2* h3  = h0;                          // h0 dead after layer-1 spmm
  float* bpart = (float*)(h2 + (size_t)NNODES * 16);  // 2*LOSS_BLOCKS

  const int T = 256;
  auto cdiv = [](int a, int b) { return (a + b - 1) / b; };

  const float4* Gu4 = (const float4*)Gu;
  const float4* Gi4 = (const float4*)Gi;

  k_zero_i<<<cdiv(NN16 + 16, T), T, 0, stream>>>(deg, NN16 + 16);
  k_count_deg<<<cdiv(E0, T), T, 0, stream>>>(eu, ei, deg, ru, ri);
  k_scan1<<<NB, 256, 0, stream>>>(deg, ptr, blk);
  k_scan_fix_cast<<<NB, 256, 0, stream>>>(ptr, blk, deg, dinv, Gu4, Gi4, h0);
  k_place<<<PLACE_B, 256, 0, stream>>>(eu, ei, ptr, ru, ri, col);

  k_spmm2<<<UBLK + IBLK, 512, 0, stream>>>(ptr, deg, col, dinv,
                                           (const uint4*)h0, (uint4*)h1);
  k_spmm2<<<UBLK + IBLK, 512, 0, stream>>>(ptr, deg, col, dinv,
                                           (const uint4*)h1, (uint4*)h2);
  k_spmm_batch<<<(3 * BB) / 16, 512, 0, stream>>>(usr, pos, neg, ptr, deg, col, dinv,
                                                  (const uint4*)h2, (uint4*)h3);

  k_loss<<<LOSS_BLOCKS, 256, 0, stream>>>(usr, pos, neg, deg, Gu4, Gi4,
                                          h1, h2, h3, bpart, cnt, out);
}

// Round 10
// 284.488 us; speedup vs baseline: 1.0293x; 1.0293x over previous
//
#include <hip/hip_runtime.h>

#define NUSERS 100000
#define NITEMS 50000
#define NNODES 150000
#define DIM 64
#define E0 600000
#define E2 (2 * E0)
#define BB 8192
#define LW 1e-4f
#define NN16 150016
#define NB 586      // cdiv(NNODES, 256)
#define LOSS_BLOCKS 256
#define UBLK 6250   // cdiv(NUSERS, 16)  (16 nodes per 512-thr block)
#define IBLK 3125   // cdiv(NITEMS, 16)
#define PLACE_B 2344  // cdiv(E0, 256)
#define CAST_B 9375   // cdiv(NNODES*16, 256)

// ---- bf16 helpers (fp32 <-> packed bf16 pair in a uint) ----
__device__ __forceinline__ float bf_lo(unsigned u) { return __uint_as_float(u << 16); }
__device__ __forceinline__ float bf_hi(unsigned u) { return __uint_as_float(u & 0xffff0000u); }
__device__ __forceinline__ unsigned rne16(float x) {
  unsigned u = __float_as_uint(x);
  return (u + 0x7fffu + ((u >> 16) & 1u)) >> 16;
}
__device__ __forceinline__ unsigned pack2(float lo, float hi) {
  return rne16(lo) | (rne16(hi) << 16);
}

// Degree count; atomic return value IS the edge's rank within its row.
// ~51us floor: 1.2M device-scope returning atomics (~23.5 Gop/s at the
// fabric coherence point). Sharding (R8) proven NOT to help.
__global__ void k_count_deg(const int* __restrict__ eu, const int* __restrict__ ei,
                            int* __restrict__ deg, int* __restrict__ ru,
                            int* __restrict__ ri) {
  int e = blockIdx.x * blockDim.x + threadIdx.x;
  if (e < E0) {
    ru[e] = atomicAdd(&deg[eu[e]], 1);
    ri[e] = atomicAdd(&deg[NUSERS + ei[e]], 1);
  }
}

// Scan pass 1: block-local exclusive scan of deg -> ptr, block sums -> blk.
__global__ void k_scan1(const int* __restrict__ deg, int* __restrict__ ptr,
                        int* __restrict__ blk) {
  __shared__ int s[256];
  int g = blockIdx.x * 256 + threadIdx.x;
  int v = (g < NNODES) ? deg[g] : 0;
  s[threadIdx.x] = v;
  __syncthreads();
  for (int off = 1; off < 256; off <<= 1) {
    int t = 0;
    if ((int)threadIdx.x >= off) t = s[threadIdx.x - off];
    __syncthreads();
    if ((int)threadIdx.x >= off) s[threadIdx.x] += t;
    __syncthreads();
  }
  if (g < NNODES) ptr[g] = s[threadIdx.x] - v;
  if (threadIdx.x == 255) blk[blockIdx.x] = s[255];
}

// Fused scan fixup: each block redundantly reduces predecessor block sums
// (<=586 ints — trivial), finalizes ptr, computes dinv. Cast deliberately
// NOT here (R9 lesson: it must co-schedule with place, not precede it).
__global__ void k_scan_fix(int* __restrict__ ptr, const int* __restrict__ blk,
                           const int* __restrict__ deg, float* __restrict__ dinv) {
  __shared__ int swsum[4];
  __shared__ int sPre;
  int tid = threadIdx.x;
  int part = 0;
  for (int j = tid; j < (int)blockIdx.x; j += 256) part += blk[j];
  for (int off = 32; off > 0; off >>= 1) part += __shfl_down(part, off);
  if ((tid & 63) == 0) swsum[tid >> 6] = part;
  __syncthreads();
  if (tid == 0) sPre = swsum[0] + swsum[1] + swsum[2] + swsum[3];
  __syncthreads();
  int g = blockIdx.x * 256 + tid;
  if (g < NNODES) {
    ptr[g] += sPre;
    int d = deg[g];
    dinv[g] = d > 0 ? rsqrtf((float)d) : 0.0f;
  }
}

// Fused: CSR placement (no atomics) + scaled-cast s0 = dinv*x (bf16).
// Block-range split: cast blocks fill the CUs underneath place's
// latency-bound scattered stores (the R7 co-scheduling win).
__global__ void k_place_cast(const int* __restrict__ eu, const int* __restrict__ ei,
                             const int* __restrict__ ptr, const int* __restrict__ ru,
                             const int* __restrict__ ri, int* __restrict__ col,
                             const float4* __restrict__ Gu4, const float4* __restrict__ Gi4,
                             const float* __restrict__ dinv, uint2* __restrict__ h0) {
  int b = blockIdx.x;
  if (b < PLACE_B) {
    int e = b * 256 + threadIdx.x;
    if (e < E0) {
      int u = eu[e];
      int it = NUSERS + ei[e];
      col[ptr[u] + ru[e]] = it;
      col[ptr[it] + ri[e]] = u;
    }
  } else {
    int t = (b - PLACE_B) * 256 + threadIdx.x;
    if (t < NNODES * 16) {
      int node = t >> 4;
      float dv = dinv[node];
      float4 v = (t < NUSERS * 16) ? Gu4[t] : Gi4[t - NUSERS * 16];
      h0[t] = make_uint2(pack2(dv * v.x, dv * v.y), pack2(dv * v.z, dv * v.w));
    }
  }
}

// Scaled-space SpMM: s_out(n) = dinv(n)^2 * sum_{c in N(n)} s_in(c).
// 2 nodes per wave; lane = 8*sub + q (8 neighbor rows in flight / node).
__global__ __launch_bounds__(512) void k_spmm2(
    const int* __restrict__ ptr, const int* __restrict__ deg,
    const int* __restrict__ col, const float* __restrict__ dinv,
    const uint4* __restrict__ h, uint4* __restrict__ hout) {
  int wid = threadIdx.x >> 6;
  int lane = threadIdx.x & 63;
  int sub = lane >> 3;
  int q = lane & 7;
  int gA, coff;
  const uint4* hsrc;
  if (blockIdx.x < UBLK) {           // user dst gather from item half
    gA = blockIdx.x * 16 + wid * 2;
    coff = NUSERS;
    hsrc = h + (size_t)NUSERS * 8;
  } else {                            // item dst gather from user half
    gA = NUSERS + (blockIdx.x - UBLK) * 16 + wid * 2;
    coff = 0;
    hsrc = h;
  }
  int gB = gA + 1;
  int stA = ptr[gA], dgA = deg[gA];
  int stB = ptr[gB], dgB = deg[gB];
  float dnA = dinv[gA], dnB = dinv[gB];
  int cA = (sub < dgA) ? col[stA + sub] : -1;
  int cB = (sub < dgB) ? col[stB + sub] : -1;
  uint4 xA = {0, 0, 0, 0}, xB = {0, 0, 0, 0};
  if (cA >= 0) xA = hsrc[(size_t)(cA - coff) * 8 + q];
  if (cB >= 0) xB = hsrc[(size_t)(cB - coff) * 8 + q];
  float aA0 = bf_lo(xA.x), aA1 = bf_hi(xA.x), aA2 = bf_lo(xA.y), aA3 = bf_hi(xA.y);
  float aA4 = bf_lo(xA.z), aA5 = bf_hi(xA.z), aA6 = bf_lo(xA.w), aA7 = bf_hi(xA.w);
  float aB0 = bf_lo(xB.x), aB1 = bf_hi(xB.x), aB2 = bf_lo(xB.y), aB3 = bf_hi(xB.y);
  float aB4 = bf_lo(xB.z), aB5 = bf_hi(xB.z), aB6 = bf_lo(xB.w), aB7 = bf_hi(xB.w);
  for (int j = stA + 8 + sub; j < stA + dgA; j += 8) {
    int c = col[j];
    uint4 x = hsrc[(size_t)(c - coff) * 8 + q];
    aA0 += bf_lo(x.x); aA1 += bf_hi(x.x); aA2 += bf_lo(x.y); aA3 += bf_hi(x.y);
    aA4 += bf_lo(x.z); aA5 += bf_hi(x.z); aA6 += bf_lo(x.w); aA7 += bf_hi(x.w);
  }
  for (int j = stB + 8 + sub; j < stB + dgB; j += 8) {
    int c = col[j];
    uint4 x = hsrc[(size_t)(c - coff) * 8 + q];
    aB0 += bf_lo(x.x); aB1 += bf_hi(x.x); aB2 += bf_lo(x.y); aB3 += bf_hi(x.y);
    aB4 += bf_lo(x.z); aB5 += bf_hi(x.z); aB6 += bf_lo(x.w); aB7 += bf_hi(x.w);
  }
  #pragma unroll
  for (int m = 8; m <= 32; m <<= 1) {
    aA0 += __shfl_xor(aA0, m); aA1 += __shfl_xor(aA1, m);
    aA2 += __shfl_xor(aA2, m); aA3 += __shfl_xor(aA3, m);
    aA4 += __shfl_xor(aA4, m); aA5 += __shfl_xor(aA5, m);
    aA6 += __shfl_xor(aA6, m); aA7 += __shfl_xor(aA7, m);
    aB0 += __shfl_xor(aB0, m); aB1 += __shfl_xor(aB1, m);
    aB2 += __shfl_xor(aB2, m); aB3 += __shfl_xor(aB3, m);
    aB4 += __shfl_xor(aB4, m); aB5 += __shfl_xor(aB5, m);
    aB6 += __shfl_xor(aB6, m); aB7 += __shfl_xor(aB7, m);
  }
  if (sub == 0) {
    float sA = dnA * dnA;
    float sB = dnB * dnB;
    hout[(size_t)gA * 8 + q] = make_uint4(pack2(aA0 * sA, aA1 * sA), pack2(aA2 * sA, aA3 * sA),
                                          pack2(aA4 * sA, aA5 * sA), pack2(aA6 * sA, aA7 * sA));
    hout[(size_t)gB * 8 + q] = make_uint4(pack2(aB0 * sB, aB1 * sB), pack2(aB2 * sB, aB3 * sB),
                                          pack2(aB4 * sB, aB5 * sB), pack2(aB6 * sB, aB7 * sB));
  }
}

__device__ __forceinline__ int decode_node(int k, const int* __restrict__ usr,
                                           const int* __restrict__ pos,
                                           const int* __restrict__ neg, int* coff) {
  if (k < BB) { *coff = NUSERS; return usr[k]; }
  if (k < 2 * BB) { *coff = 0; return NUSERS + pos[k - BB]; }
  *coff = 0; return NUSERS + neg[k - 2 * BB];
}

// Layer-3 SpMM only at the <=3*BB batch nodes (duplicate writes identical).
__global__ __launch_bounds__(512) void k_spmm_batch(
    const int* __restrict__ usr, const int* __restrict__ pos, const int* __restrict__ neg,
    const int* __restrict__ ptr, const int* __restrict__ deg,
    const int* __restrict__ col, const float* __restrict__ dinv,
    const uint4* __restrict__ h, uint4* __restrict__ hout) {
  int wid = threadIdx.x >> 6;
  int lane = threadIdx.x & 63;
  int sub = lane >> 3;
  int q = lane & 7;
  int k0 = blockIdx.x * 16 + wid * 2;
  int cofA, cofB;
  int gA = decode_node(k0, usr, pos, neg, &cofA);
  int gB = decode_node(k0 + 1, usr, pos, neg, &cofB);
  const uint4* hsA = h + (size_t)cofA * 8;
  const uint4* hsB = h + (size_t)cofB * 8;
  int stA = ptr[gA], dgA = deg[gA];
  int stB = ptr[gB], dgB = deg[gB];
  float dnA = dinv[gA], dnB = dinv[gB];
  int cA = (sub < dgA) ? col[stA + sub] : -1;
  int cB = (sub < dgB) ? col[stB + sub] : -1;
  uint4 xA = {0, 0, 0, 0}, xB = {0, 0, 0, 0};
  if (cA >= 0) xA = hsA[(size_t)(cA - cofA) * 8 + q];
  if (cB >= 0) xB = hsB[(size_t)(cB - cofB) * 8 + q];
  float aA0 = bf_lo(xA.x), aA1 = bf_hi(xA.x), aA2 = bf_lo(xA.y), aA3 = bf_hi(xA.y);
  float aA4 = bf_lo(xA.z), aA5 = bf_hi(xA.z), aA6 = bf_lo(xA.w), aA7 = bf_hi(xA.w);
  float aB0 = bf_lo(xB.x), aB1 = bf_hi(xB.x), aB2 = bf_lo(xB.y), aB3 = bf_hi(xB.y);
  float aB4 = bf_lo(xB.z), aB5 = bf_hi(xB.z), aB6 = bf_lo(xB.w), aB7 = bf_hi(xB.w);
  for (int j = stA + 8 + sub; j < stA + dgA; j += 8) {
    int c = col[j];
    uint4 x = hsA[(size_t)(c - cofA) * 8 + q];
    aA0 += bf_lo(x.x); aA1 += bf_hi(x.x); aA2 += bf_lo(x.y); aA3 += bf_hi(x.y);
    aA4 += bf_lo(x.z); aA5 += bf_hi(x.z); aA6 += bf_lo(x.w); aA7 += bf_hi(x.w);
  }
  for (int j = stB + 8 + sub; j < stB + dgB; j += 8) {
    int c = col[j];
    uint4 x = hsB[(size_t)(c - cofB) * 8 + q];
    aB0 += bf_lo(x.x); aB1 += bf_hi(x.x); aB2 += bf_lo(x.y); aB3 += bf_hi(x.y);
    aB4 += bf_lo(x.z); aB5 += bf_hi(x.z); aB6 += bf_lo(x.w); aB7 += bf_hi(x.w);
  }
  #pragma unroll
  for (int m = 8; m <= 32; m <<= 1) {
    aA0 += __shfl_xor(aA0, m); aA1 += __shfl_xor(aA1, m);
    aA2 += __shfl_xor(aA2, m); aA3 += __shfl_xor(aA3, m);
    aA4 += __shfl_xor(aA4, m); aA5 += __shfl_xor(aA5, m);
    aA6 += __shfl_xor(aA6, m); aA7 += __shfl_xor(aA7, m);
    aB0 += __shfl_xor(aB0, m); aB1 += __shfl_xor(aB1, m);
    aB2 += __shfl_xor(aB2, m); aB3 += __shfl_xor(aB3, m);
    aB4 += __shfl_xor(aB4, m); aB5 += __shfl_xor(aB5, m);
    aB6 += __shfl_xor(aB6, m); aB7 += __shfl_xor(aB7, m);
  }
  if (sub == 0) {
    float sA = dnA * dnA;
    float sB = dnB * dnB;
    hout[(size_t)gA * 8 + q] = make_uint4(pack2(aA0 * sA, aA1 * sA), pack2(aA2 * sA, aA3 * sA),
                                          pack2(aA4 * sA, aA5 * sA), pack2(aA6 * sA, aA7 * sA));
    hout[(size_t)gB * 8 + q] = make_uint4(pack2(aB0 * sB, aB1 * sB), pack2(aB2 * sB, aB3 * sB),
                                          pack2(aB4 * sB, aB5 * sB), pack2(aB6 * sB, aB7 * sB));
  }
}

// Fused batch gather + layer sum + BPR loss + last-block final reduce.
__global__ void k_loss(const int* __restrict__ usr, const int* __restrict__ pos,
                       const int* __restrict__ neg, const int* __restrict__ deg,
                       const float4* __restrict__ Gu4, const float4* __restrict__ Gi4,
                       const uint2* __restrict__ h1, const uint2* __restrict__ h2,
                       const uint2* __restrict__ h3, float* __restrict__ bpart,
                       int* __restrict__ cnt, float* __restrict__ out) {
  __shared__ float sL[4], sR[4];
  __shared__ int sDone;
  int wid = threadIdx.x >> 6;
  int lane = threadIdx.x & 63;
  int r = lane >> 4;
  int q = lane & 15;
  int gw = blockIdx.x * 4 + wid;
  int nw = gridDim.x * 4;
  const float s = 0.25f;
  float accL = 0.0f, accR = 0.0f;
  for (int b4 = gw; b4 < BB / 4; b4 += nw) {
    int b = b4 * 4 + r;
    int iu = usr[b], ip = pos[b], ig = neg[b];
    float sdu = sqrtf((float)deg[iu]);
    float sdp = sqrtf((float)deg[NUSERS + ip]);
    float sdn = sqrtf((float)deg[NUSERS + ig]);
    size_t ou = (size_t)iu * 16 + q;
    size_t op = ((size_t)NUSERS + ip) * 16 + q;
    size_t on = ((size_t)NUSERS + ig) * 16 + q;
    float4 u = Gu4[ou];
    float4 p = Gi4[(size_t)ip * 16 + q];
    float4 g = Gi4[(size_t)ig * 16 + q];
    float4 su = {0, 0, 0, 0}, sp = {0, 0, 0, 0}, sg = {0, 0, 0, 0};
    uint2 v;
    v = h1[ou]; su.x += bf_lo(v.x); su.y += bf_hi(v.x); su.z += bf_lo(v.y); su.w += bf_hi(v.y);
    v = h2[ou]; su.x += bf_lo(v.x); su.y += bf_hi(v.x); su.z += bf_lo(v.y); su.w += bf_hi(v.y);
    v = h3[ou]; su.x += bf_lo(v.x); su.y += bf_hi(v.x); su.z += bf_lo(v.y); su.w += bf_hi(v.y);
    v = h1[op]; sp.x += bf_lo(v.x); sp.y += bf_hi(v.x); sp.z += bf_lo(v.y); sp.w += bf_hi(v.y);
    v = h2[op]; sp.x += bf_lo(v.x); sp.y += bf_hi(v.x); sp.z += bf_lo(v.y); sp.w += bf_hi(v.y);
    v = h3[op]; sp.x += bf_lo(v.x); sp.y += bf_hi(v.x); sp.z += bf_lo(v.y); sp.w += bf_hi(v.y);
    v = h1[on]; sg.x += bf_lo(v.x); sg.y += bf_hi(v.x); sg.z += bf_lo(v.y); sg.w += bf_hi(v.y);
    v = h2[on]; sg.x += bf_lo(v.x); sg.y += bf_hi(v.x); sg.z += bf_lo(v.y); sg.w += bf_hi(v.y);
    v = h3[on]; sg.x += bf_lo(v.x); sg.y += bf_hi(v.x); sg.z += bf_lo(v.y); sg.w += bf_hi(v.y);
    u.x = (u.x + sdu * su.x) * s; u.y = (u.y + sdu * su.y) * s;
    u.z = (u.z + sdu * su.z) * s; u.w = (u.w + sdu * su.w) * s;
    p.x = (p.x + sdp * sp.x) * s; p.y = (p.y + sdp * sp.y) * s;
    p.z = (p.z + sdp * sp.z) * s; p.w = (p.w + sdp * sp.w) * s;
    g.x = (g.x + sdn * sg.x) * s; g.y = (g.y + sdn * sg.y) * s;
    g.z = (g.z + sdn * sg.z) * s; g.w = (g.w + sdn * sg.w) * s;
    float dp = u.x * p.x + u.y * p.y + u.z * p.z + u.w * p.w;
    float dn = u.x * g.x + u.y * g.y + u.z * g.z + u.w * g.w;
    float rg = u.x * u.x + u.y * u.y + u.z * u.z + u.w * u.w
             + p.x * p.x + p.y * p.y + p.z * p.z + p.w * p.w
             + g.x * g.x + g.y * g.y + g.z * g.z + g.w * g.w;
    #pragma unroll
    for (int m = 1; m <= 8; m <<= 1) {
      dp += __shfl_xor(dp, m);
      dn += __shfl_xor(dn, m);
      rg += __shfl_xor(rg, m);
    }
    if (q == 0) {
      float diff = dp - dn;
      accL -= fminf(diff, 0.0f) - log1pf(expf(-fabsf(diff)));
      accR += rg;
    }
  }
  accL += __shfl_xor(accL, 16); accR += __shfl_xor(accR, 16);
  accL += __shfl_xor(accL, 32); accR += __shfl_xor(accR, 32);
  if (lane == 0) { sL[wid] = accL; sR[wid] = accR; }
  __syncthreads();
  if (threadIdx.x == 0) {
    bpart[blockIdx.x] = sL[0] + sL[1] + sL[2] + sL[3];
    bpart[LOSS_BLOCKS + blockIdx.x] = sR[0] + sR[1] + sR[2] + sR[3];
    __threadfence();
    sDone = (atomicAdd(cnt, 1) == LOSS_BLOCKS - 1) ? 1 : 0;
  }
  __syncthreads();
  if (sDone && threadIdx.x < 64) {
    __threadfence();  // acquire: other blocks' bpart stores
    int ln = threadIdx.x;
    float l = bpart[ln] + bpart[ln + 64] + bpart[ln + 128] + bpart[ln + 192];
    float rr = bpart[LOSS_BLOCKS + ln] + bpart[LOSS_BLOCKS + ln + 64]
             + bpart[LOSS_BLOCKS + ln + 128] + bpart[LOSS_BLOCKS + ln + 192];
    for (int off = 32; off > 0; off >>= 1) {
      l += __shfl_down(l, off);
      rr += __shfl_down(rr, off);
    }
    if (ln == 0) out[0] = l * (1.0f / BB) + LW * 0.5f * rr * (1.0f / BB);
  }
}

extern "C" void kernel_launch(void* const* d_in, const int* in_sizes, int n_in,
                              void* d_out, int out_size, void* d_ws, size_t ws_size,
                              hipStream_t stream) {
  const float* Gu = (const float*)d_in[0];
  const float* Gi = (const float*)d_in[1];
  const int* eu  = (const int*)d_in[2];
  const int* ei  = (const int*)d_in[3];
  const int* usr = (const int*)d_in[4];
  const int* pos = (const int*)d_in[5];
  const int* neg = (const int*)d_in[6];
  float* out = (float*)d_out;

  // Workspace: ~8 MB ints + 57.6 MB h (h3 reuses h0) = ~66 MB.
  int* deg   = (int*)d_ws;                 // NN16
  int* cnt   = deg + NN16;                 // 16 (zeroed with deg via memset)
  int* ptr   = cnt + 16;                   // NN16
  int* blk   = ptr + NN16;                 // 1024
  int* ru    = blk + 1024;                 // E0
  int* ri    = ru + E0;                    // E0
  int* col   = ri + E0;                    // E2
  float* dinv = (float*)(col + E2);        // NN16
  uint2* h0  = (uint2*)(dinv + NN16);      // NNODES*16 uint2 each (19.2 MB)
  uint2* h1  = h0 + (size_t)NNODES * 16;
  uint2* h2  = h1 + (size_t)NNODES * 16;
  uint2* h3  = h0;                          // h0 dead after layer-1 spmm
  float* bpart = (float*)(h2 + (size_t)NNODES * 16);  // 2*LOSS_BLOCKS

  const int T = 256;
  auto cdiv = [](int a, int b) { return (a + b - 1) / b; };

  const float4* Gu4 = (const float4*)Gu;
  const float4* Gi4 = (const float4*)Gi;

  hipMemsetAsync(deg, 0, (size_t)(NN16 + 16) * sizeof(int), stream);
  k_count_deg<<<cdiv(E0, T), T, 0, stream>>>(eu, ei, deg, ru, ri);
  k_scan1<<<NB, 256, 0, stream>>>(deg, ptr, blk);
  k_scan_fix<<<NB, 256, 0, stream>>>(ptr, blk, deg, dinv);
  k_place_cast<<<PLACE_B + CAST_B, 256, 0, stream>>>(eu, ei, ptr, ru, ri, col,
                                                     Gu4, Gi4, dinv, h0);

  k_spmm2<<<UBLK + IBLK, 512, 0, stream>>>(ptr, deg, col, dinv,
                                           (const uint4*)h0, (uint4*)h1);
  k_spmm2<<<UBLK + IBLK, 512, 0, stream>>>(ptr, deg, col, dinv,
                                           (const uint4*)h1, (uint4*)h2);
  k_spmm_batch<<<(3 * BB) / 16, 512, 0, stream>>>(usr, pos, neg, ptr, deg, col, dinv,
                                                  (const uint4*)h2, (uint4*)h3);

  k_loss<<<LOSS_BLOCKS, 256, 0, stream>>>(usr, pos, neg, deg, Gu4, Gi4,
                                          h1, h2, h3, bpart, cnt, out);
}